// Round 4
// baseline (71.069 us; speedup 1.0000x reference)
//
#include <hip/hip_runtime.h>
#include <hip/hip_bf16.h>

#define DIM 384
#define RED 16
#define PAIR 128
#define B 2
#define M 512
#define EPSV 1e-5f

typedef float f32x4 __attribute__((ext_vector_type(4)));

// ---------------------------------------------------------------------------
// K1: per (b,m) row: LayerNorm(384) -> xr[16] = xn @ w_red + b_red
//     -> T[16][128] : T[i][p] = sum_j xr[j] * w_out[(i*16+j)*128 + p]
// grid = B*M = 1024 blocks, block = 128 threads
// ---------------------------------------------------------------------------
__global__ __launch_bounds__(128) void opm_k1(
    const float* __restrict__ x, const float* __restrict__ g,
    const float* __restrict__ be, const float* __restrict__ w_red,
    const float* __restrict__ b_red, const float* __restrict__ w_out,
    float* __restrict__ xr_out, float* __restrict__ T_out) {
  const int row = blockIdx.x;           // b*M + m
  const int tid = threadIdx.x;          // 0..127
  const float* xrow = x + (size_t)row * DIM;

  __shared__ float xn[DIM];
  __shared__ float xr_s[RED];
  __shared__ float rs[2][2];
  __shared__ float psum[8][RED];

  // load 3 elems/thread
  float v0 = xrow[tid];
  float v1 = xrow[tid + 128];
  float v2 = xrow[tid + 256];
  float s  = v0 + v1 + v2;
  float sq = v0 * v0 + v1 * v1 + v2 * v2;
  // wave reduce (wave = 64 lanes)
  #pragma unroll
  for (int off = 32; off > 0; off >>= 1) {
    s  += __shfl_down(s, off);
    sq += __shfl_down(sq, off);
  }
  if ((tid & 63) == 0) { rs[0][tid >> 6] = s; rs[1][tid >> 6] = sq; }
  __syncthreads();
  const float mean = (rs[0][0] + rs[0][1]) * (1.0f / DIM);
  const float var  = (rs[1][0] + rs[1][1]) * (1.0f / DIM) - mean * mean;
  const float rstd = rsqrtf(var + EPSV);

  xn[tid]       = (v0 - mean) * rstd * g[tid]       + be[tid];
  xn[tid + 128] = (v1 - mean) * rstd * g[tid + 128] + be[tid + 128];
  xn[tid + 256] = (v2 - mean) * rstd * g[tid + 256] + be[tid + 256];
  __syncthreads();

  // xr: 16 outputs, 8 partial-sums each over 48 dims
  {
    const int r = tid & 15;
    const int part = tid >> 4;  // 0..7
    float ps = 0.0f;
    const int d0 = part * 48;
    #pragma unroll 8
    for (int d = d0; d < d0 + 48; ++d) ps += xn[d] * w_red[d * RED + r];
    psum[part][r] = ps;
  }
  __syncthreads();
  if (tid < RED) {
    float v = b_red[tid];
    #pragma unroll
    for (int q = 0; q < 8; ++q) v += psum[q][tid];
    xr_s[tid] = v;
    xr_out[(size_t)row * RED + tid] = v;
  }
  __syncthreads();

  // T row: thread p handles all 16 i
  {
    const int p = tid;  // 0..127
    const float* W = w_out + p;
    float* Trow = T_out + (size_t)row * RED * PAIR + p;
    #pragma unroll
    for (int i = 0; i < RED; ++i) {
      float acc = 0.0f;
      #pragma unroll
      for (int j = 0; j < RED; ++j) acc += xr_s[j] * W[(i * RED + j) * PAIR];
      Trow[i * PAIR] = acc;
    }
  }
}

// ---------------------------------------------------------------------------
// K2: out[b,m,n,p] = b_out[p] + sum_i xr[b,m,i] * T[b,n,i,p]
// block = 256 threads. Each thread: one n, 4 consecutive p (float4 stores),
// loops over 64 m. block tile: 64 m x 8 n x 128 p.
// grid = B*(M/64)*(M/8) = 2*8*64 = 1024
// T read traffic = 1024 blocks * 64 KB = 64 MB (L2-resident per XCD).
// ---------------------------------------------------------------------------
__global__ __launch_bounds__(256) void opm_k2(
    const float* __restrict__ xr, const float* __restrict__ T,
    const float* __restrict__ b_out, float* __restrict__ out) {
  const int nc  = blockIdx.x & 63;          // n-chunk (M/8 = 64)
  const int mt  = (blockIdx.x >> 6) & 7;    // m-tile  (M/64 = 8)
  const int b   = blockIdx.x >> 9;
  const int tid = threadIdx.x;
  const int p4  = (tid & 31) * 4;           // first of 4 consecutive p
  const int n   = nc * 8 + (tid >> 5);      // this thread's n

  __shared__ float a_s[64 * RED];           // xr m-tile: 64 rows x 16 (4 KB)

  // load 64x16 = 1024 floats with 256 threads (4 each)
  {
    const float* src = xr + (size_t)(b * M + mt * 64) * RED;
    #pragma unroll
    for (int k = 0; k < 4; ++k) a_s[tid + k * 256] = src[tid + k * 256];
  }

  const f32x4 bias = *reinterpret_cast<const f32x4*>(&b_out[p4]);

  // T fragment for this (n, p4..p4+3): 16 x f32x4 = 64 VGPRs
  f32x4 t[RED];
  const float* Tb = T + ((size_t)(b * M + n) * RED) * PAIR + p4;
  #pragma unroll
  for (int i = 0; i < RED; ++i)
    t[i] = *reinterpret_cast<const f32x4*>(&Tb[i * PAIR]);
  __syncthreads();

  float* outp = out + (((size_t)(b * M + mt * 64) * M + n) * PAIR) + p4;
  #pragma unroll 4
  for (int m = 0; m < 64; ++m) {
    const f32x4 a0 = *reinterpret_cast<const f32x4*>(&a_s[m * RED + 0]);
    const f32x4 a1 = *reinterpret_cast<const f32x4*>(&a_s[m * RED + 4]);
    const f32x4 a2 = *reinterpret_cast<const f32x4*>(&a_s[m * RED + 8]);
    const f32x4 a3 = *reinterpret_cast<const f32x4*>(&a_s[m * RED + 12]);
    f32x4 acc = bias;
    acc += a0.x * t[0];
    acc += a0.y * t[1];
    acc += a0.z * t[2];
    acc += a0.w * t[3];
    acc += a1.x * t[4];
    acc += a1.y * t[5];
    acc += a1.z * t[6];
    acc += a1.w * t[7];
    acc += a2.x * t[8];
    acc += a2.y * t[9];
    acc += a2.z * t[10];
    acc += a2.w * t[11];
    acc += a3.x * t[12];
    acc += a3.y * t[13];
    acc += a3.z * t[14];
    acc += a3.w * t[15];
    __builtin_nontemporal_store(acc, reinterpret_cast<f32x4*>(outp));
    outp += (size_t)M * PAIR;   // next m
  }
}

extern "C" void kernel_launch(void* const* d_in, const int* in_sizes, int n_in,
                              void* d_out, int out_size, void* d_ws, size_t ws_size,
                              hipStream_t stream) {
  const float* x       = (const float*)d_in[0];
  const float* ln_g    = (const float*)d_in[1];
  const float* ln_b    = (const float*)d_in[2];
  const float* w_red   = (const float*)d_in[3];
  const float* b_red   = (const float*)d_in[4];
  const float* w_out   = (const float*)d_in[5];
  const float* b_out   = (const float*)d_in[6];
  float* out = (float*)d_out;

  float* xr = (float*)d_ws;                      // B*M*RED   = 16384 floats (64 KB)
  float* T  = xr + (size_t)B * M * RED;          // B*M*RED*PAIR = 8 MB

  opm_k1<<<B * M, 128, 0, stream>>>(x, ln_g, ln_b, w_red, b_red, w_out, xr, T);
  opm_k2<<<B * (M / 64) * (M / 8), 256, 0, stream>>>(xr, T, b_out, out);
}

// Round 5
// 57.320 us; speedup vs baseline: 1.2399x; 1.2399x over previous
//
#include <hip/hip_runtime.h>
#include <hip/hip_bf16.h>

#define DIM 384
#define RED 16
#define PAIR 128
#define B 2
#define M 512
#define EPSV 1e-5f

typedef float f32x4 __attribute__((ext_vector_type(4)));
typedef short bf16x8 __attribute__((ext_vector_type(8)));

__device__ __forceinline__ unsigned short f2bf(float f) {
  union { float f; unsigned u; } v; v.f = f;
  unsigned r = v.u + 0x7fffu + ((v.u >> 16) & 1u);   // RTN-even
  return (unsigned short)(r >> 16);
}

// ---------------------------------------------------------------------------
// K1: per (b,m) row: LayerNorm(384) -> xr[16] (bf16)
//     -> T_bf[row][p][i] = bf16( sum_j xr[j] * w_out[(i*16+j)*128 + p] )
// grid = B*M = 1024 blocks, block = 128 threads
// ---------------------------------------------------------------------------
__global__ __launch_bounds__(128) void opm_k1(
    const float* __restrict__ x, const float* __restrict__ g,
    const float* __restrict__ be, const float* __restrict__ w_red,
    const float* __restrict__ b_red, const float* __restrict__ w_out,
    unsigned short* __restrict__ xr_bf, unsigned short* __restrict__ T_bf) {
  const int row = blockIdx.x;           // b*M + m
  const int tid = threadIdx.x;          // 0..127
  const float* xrow = x + (size_t)row * DIM;

  __shared__ float xn[DIM];
  __shared__ float xr_s[RED];
  __shared__ float rs[2][2];
  __shared__ float psum[8][RED];

  float v0 = xrow[tid];
  float v1 = xrow[tid + 128];
  float v2 = xrow[tid + 256];
  float s  = v0 + v1 + v2;
  float sq = v0 * v0 + v1 * v1 + v2 * v2;
  #pragma unroll
  for (int off = 32; off > 0; off >>= 1) {
    s  += __shfl_down(s, off);
    sq += __shfl_down(sq, off);
  }
  if ((tid & 63) == 0) { rs[0][tid >> 6] = s; rs[1][tid >> 6] = sq; }
  __syncthreads();
  const float mean = (rs[0][0] + rs[0][1]) * (1.0f / DIM);
  const float var  = (rs[1][0] + rs[1][1]) * (1.0f / DIM) - mean * mean;
  const float rstd = rsqrtf(var + EPSV);

  xn[tid]       = (v0 - mean) * rstd * g[tid]       + be[tid];
  xn[tid + 128] = (v1 - mean) * rstd * g[tid + 128] + be[tid + 128];
  xn[tid + 256] = (v2 - mean) * rstd * g[tid + 256] + be[tid + 256];
  __syncthreads();

  {
    const int r = tid & 15;
    const int part = tid >> 4;  // 0..7
    float ps = 0.0f;
    const int d0 = part * 48;
    #pragma unroll 8
    for (int d = d0; d < d0 + 48; ++d) ps += xn[d] * w_red[d * RED + r];
    psum[part][r] = ps;
  }
  __syncthreads();
  if (tid < RED) {
    float v = b_red[tid];
    #pragma unroll
    for (int q = 0; q < 8; ++q) v += psum[q][tid];
    xr_s[tid] = v;
    xr_bf[(size_t)row * RED + tid] = f2bf(v);
  }
  __syncthreads();

  // T row, layout [p][i] (i contiguous), bf16
  {
    const int p = tid;  // 0..127
    const float* W = w_out + p;
    float acc[RED];
    #pragma unroll
    for (int i = 0; i < RED; ++i) {
      float a = 0.0f;
      #pragma unroll
      for (int j = 0; j < RED; ++j) a += xr_s[j] * W[(i * RED + j) * PAIR];
      acc[i] = a;
    }
    unsigned int w0[4], w1[4];
    #pragma unroll
    for (int k = 0; k < 4; ++k) {
      w0[k] = (unsigned)f2bf(acc[2*k])     | ((unsigned)f2bf(acc[2*k+1]) << 16);
      w1[k] = (unsigned)f2bf(acc[8+2*k])   | ((unsigned)f2bf(acc[8+2*k+1]) << 16);
    }
    unsigned int* dst = (unsigned int*)(T_bf + ((size_t)row * PAIR + p) * RED);
    #pragma unroll
    for (int k = 0; k < 4; ++k) { dst[k] = w0[k]; dst[4+k] = w1[k]; }
  }
}

// ---------------------------------------------------------------------------
// K2 (MFMA): out[b,m,n,p] = b_out[p] + sum_i xr[b,m,i] * T[b,n,i,p]
// One wave per n. Per wave: 8 B-frags (16i x 16p each, K padded to 32),
// loop over 4 m-subtiles of 16: 1 A-frag load + 8 MFMA + 32 dword stores.
// block = 256 thr (4 waves = 4 consecutive n), tile = 64 m x 4 n x 128 p.
// grid = B * (M/64) * (M/4) = 2*8*128 = 2048
// ---------------------------------------------------------------------------
__global__ __launch_bounds__(256) void opm_k2(
    const unsigned short* __restrict__ xr_bf, const unsigned short* __restrict__ T_bf,
    const float* __restrict__ b_out, float* __restrict__ out) {
  const int nb = blockIdx.x & 127;          // n-group (M/4 = 128)
  const int mt = (blockIdx.x >> 7) & 7;     // m-tile  (M/64 = 8)
  const int b  = blockIdx.x >> 10;
  const int wave = threadIdx.x >> 6;
  const int lane = threadIdx.x & 63;
  const int q = lane >> 4;                  // 0..3 (k-quad)
  const int r = lane & 15;                  // row (A) / col (B,D)
  const int n = nb * 4 + wave;

  // B fragments: bv[pb] lane(q,r) holds T[n][i=8q..8q+7][pb*16+r]; q>=2 -> zeros (K pad)
  bf16x8 bv[8];
  const unsigned short* Tb = T_bf + ((size_t)(b * M + n) * PAIR) * RED;
  #pragma unroll
  for (int pb = 0; pb < 8; ++pb) {
    bf16x8 v = {0, 0, 0, 0, 0, 0, 0, 0};
    if (q < 2) v = *(const bf16x8*)(Tb + (pb * 16 + r) * RED + q * 8);
    bv[pb] = v;
  }
  float bias[8];
  #pragma unroll
  for (int pb = 0; pb < 8; ++pb) bias[pb] = b_out[pb * 16 + r];

  const size_t MROW = (size_t)M * PAIR;     // out stride per m

  #pragma unroll
  for (int ms = 0; ms < 4; ++ms) {
    const int m0 = mt * 64 + ms * 16;
    // A fragment: lane(q,r) holds xr[m0+r][8q..8q+7]; q>=2 -> zeros
    bf16x8 av = {0, 0, 0, 0, 0, 0, 0, 0};
    if (q < 2) av = *(const bf16x8*)(xr_bf + (size_t)(b * M + m0 + r) * RED + q * 8);

    float* outbase = out + ((size_t)(b * M + m0 + q * 4) * M + n) * PAIR + r;
    #pragma unroll
    for (int pb = 0; pb < 8; ++pb) {
      f32x4 acc = {bias[pb], bias[pb], bias[pb], bias[pb]};
      acc = __builtin_amdgcn_mfma_f32_16x16x32_bf16(av, bv[pb], acc, 0, 0, 0);
      float* o = outbase + pb * 16;
      o[0]        = acc[0];   // m = m0 + q*4 + 0
      o[MROW]     = acc[1];   // m = m0 + q*4 + 1
      o[2 * MROW] = acc[2];
      o[3 * MROW] = acc[3];
    }
  }
}

extern "C" void kernel_launch(void* const* d_in, const int* in_sizes, int n_in,
                              void* d_out, int out_size, void* d_ws, size_t ws_size,
                              hipStream_t stream) {
  const float* x       = (const float*)d_in[0];
  const float* ln_g    = (const float*)d_in[1];
  const float* ln_b    = (const float*)d_in[2];
  const float* w_red   = (const float*)d_in[3];
  const float* b_red   = (const float*)d_in[4];
  const float* w_out   = (const float*)d_in[5];
  const float* b_out   = (const float*)d_in[6];
  float* out = (float*)d_out;

  unsigned short* xr_bf = (unsigned short*)d_ws;            // B*M*16 u16 = 32 KB
  unsigned short* T_bf  = xr_bf + (size_t)B * M * RED;      // B*M*128*16 u16 = 4 MB

  opm_k1<<<B * M, 128, 0, stream>>>(x, ln_g, ln_b, w_red, b_red, w_out, xr_bf, T_bf);
  opm_k2<<<B * (M / 64) * (M / 4), 256, 0, stream>>>(xr_bf, T_bf, b_out, out);
}